// Round 17
// baseline (33.574 us; speedup 1.0000x reference)
//
#include <hip/hip_runtime.h>
#include <hip/hip_bf16.h>

typedef __attribute__((ext_vector_type(8))) short bf16x8;
typedef __attribute__((ext_vector_type(4))) float f32x4;

#define NPIX 32768

// ws byte layout (fragment-order packed weights):
//   [0, 32768)      W1p bf16: elem ((kk*4+dt)*64+ln)*8+cc  (kk<8, dt<4)
//   [32768, 51200)  W2p bf16: elem ((kk*9+et)*64+ln)*8+cc  (kk<2, et<9)
//   [51200, 51456)  b1f f32 [64]  (BN-folded bias)
// -> every MFMA B-fragment load is ONE coalesced 1KB wave access at a
//    wave-uniform base (identical across waves; L1-resident).

__device__ __forceinline__ ushort f2bf(float f) {
    __hip_bfloat16 h = __float2bfloat16(f);   // single v_cvt, RNE
    ushort u; __builtin_memcpy(&u, &h, 2);
    return u;
}

__global__ __launch_bounds__(256) void fold_kernel(
        const float* __restrict__ W1, const float* __restrict__ b1,
        const float* __restrict__ gamma, const float* __restrict__ beta,
        const float* __restrict__ mean, const float* __restrict__ var,
        const float* __restrict__ W2, void* __restrict__ ws) {
    ushort* w1p = (ushort*)ws;
    ushort* w2p = (ushort*)ws + 16384;
    float*  b1f = (float*)((char*)ws + 51200);
    int tid = blockIdx.x * 256 + threadIdx.x;
    if (tid < 16384) {
        int cc = tid & 7, ln = (tid >> 3) & 63, dt = (tid >> 9) & 3, kk = tid >> 11;
        int d = dt * 16 + (ln & 15);
        int c = kk * 32 + ((ln >> 4) & 3) * 8 + cc;
        float scale = gamma[d] * rsqrtf(var[d] + 1e-3f);
        w1p[tid] = f2bf(W1[c * 64 + d] * scale);
    }
    if (tid < 9216) {
        int cc = tid & 7, ln = (tid >> 3) & 63, rem = tid >> 9;  // rem<18
        int et = rem % 9, kk = rem / 9;
        int e = et * 16 + (ln & 15);
        int dcol = kk * 32 + ((ln >> 4) & 3) * 8 + cc;
        w2p[tid] = f2bf(W2[dcol * 144 + e]);
    }
    if (tid < 64) {
        float scale = gamma[tid] * rsqrtf(var[tid] + 1e-3f);
        b1f[tid] = (b1[tid] - mean[tid]) * scale + beta[tid];
    }
}

// R15 weight layout + R12 geometry: 8 px/wave -> 4096 waves = 16 waves/CU
// (2x R15's concurrency). R12's regression cause (scattered per-lane B
// loads duplicated per wave) is gone: B loads are wave-uniform coalesced
// 1KB L1 hits, nearly free to duplicate. MFMA 16x16 with A-rows 8..15
// duplicating rows 0..7 (q8 = r16&7); only q<8 results stored (MfmaUtil
// ~3% -> wasted half-tile free).
// Wave-private LDS arenas (5120 B per wave), ZERO barriers:
//   phase A: xs bf16 [8 rows][512 B] @0, XOR-swizzled
//   phase B: hs bf16 [8 rows][128 B] @4096, swizzled
//   phase C: ks f32  [8 rows][148]   @0 (4736 B; aliases xs -- safe:
//            written after all xs/hs LDS reads, per-wave in-order)
// Block = 32 px (half row), 4 waves, grid 1024 = 4 blocks/CU.
// XCD k owns image k (b = bid&7) for halo L2 locality.
__global__ __launch_bounds__(256, 4) void fused_kernel(
        const float* __restrict__ x, const void* __restrict__ ws,
        const float* __restrict__ b2, float* __restrict__ ker,
        float* __restrict__ out) {
    __shared__ __align__(16) char smem[20480];
    const int t = threadIdx.x;
    const int wv = t >> 6, ln = t & 63;
    char* arena = smem + wv * 5120;
    const int bid = (int)blockIdx.x;
    const int xcd = bid & 7;                 // image index (B == 8 XCDs)
    const int idx = bid >> 3;                // [0,128): half-row within image
    const int row = idx >> 1, half = idx & 1;
    const int lb  = xcd * 64 + row;          // b*64 + i
    const int pw  = lb * 64 + half * 32 + wv * 8;   // wave's first pixel
    const int j0  = half * 32 + wv * 8;             // wave's first column
    const ushort* w1p = (const ushort*)ws;
    const ushort* w2p = (const ushort*)ws + 16384;
    const float*  b1f = (const float*)((const char*)ws + 51200);
    const int r16 = ln & 15, g = ln >> 4;
    const int q8 = r16 & 7;                  // A-row remap (dup rows 8..15)

    // ---- stage wave's 8 x-rows: f32 -> bf16, XOR-swizzled ----
    {
        const float4* xg = (const float4*)(x + (size_t)pw * 256);
        #pragma unroll
        for (int it = 0; it < 8; it++) {
            float4 v = xg[it * 64 + ln];
            ushort4 b4; b4.x = f2bf(v.x); b4.y = f2bf(v.y);
            b4.z = f2bf(v.z); b4.w = f2bf(v.w);
            int bcol = (ln * 8) ^ (it << 4);
            *(ushort4*)(arena + it * 512 + bcol) = b4;
        }
    }

    // ---- GEMM1: 8 px x 64 d; A from arena xs (row q8), B coalesced W1p ----
    f32x4 acc[4];
    #pragma unroll
    for (int dt = 0; dt < 4; dt++) {
        float bv = b1f[dt * 16 + r16];
        acc[dt] = (f32x4){bv, bv, bv, bv};
    }
    #pragma unroll
    for (int kk = 0; kk < 8; kk++) {
        int bcA = (kk * 64 + g * 16) ^ (q8 << 4);
        bf16x8 av = *(const bf16x8*)(arena + q8 * 512 + bcA);
        #pragma unroll
        for (int dt = 0; dt < 4; dt++) {
            bf16x8 bv = *(const bf16x8*)(w1p + (((kk * 4 + dt) << 6) + ln) * 8);
            acc[dt] = __builtin_amdgcn_mfma_f32_16x16x32_bf16(av, bv, acc[dt], 0, 0, 0);
        }
    }

    // relu -> bf16 -> hs (arena+4096, rows 0..7, swizzled); q>=8 discarded
    #pragma unroll
    for (int dt = 0; dt < 4; dt++) {
        #pragma unroll
        for (int r = 0; r < 4; r++) {
            int q = g * 4 + r;                        // C/D row
            if (q < 8) {
                int bcol = ((dt * 16 + r16) * 2) ^ (q << 4);
                *(ushort*)(arena + 4096 + q * 128 + bcol) = f2bf(fmaxf(acc[dt][r], 0.f));
            }
        }
    }

    // ---- invol window preload: latency hides under GEMM2 ----
    const int i  = lb & 63;
    const f32x4* xv4 = (const f32x4*)x;
    const f32x4 z4 = {0.f, 0.f, 0.f, 0.f};
    f32x4 wa[3], wb[3], wc[3], wd[3];   // cols j-1, j, j+1, j+2
    #pragma unroll
    for (int r = 0; r < 3; r++) {
        int rw = i + r - 1;
        bool rv = (unsigned)rw < 64u;
        const size_t rb = (size_t)(lb + r - 1) * 64;
        wa[r] = (rv && j0 > 0) ? xv4[(rb + (j0 - 1)) * 64 + ln] : z4;
        wb[r] = rv ? xv4[(rb + j0) * 64 + ln] : z4;
        wc[r] = rv ? xv4[(rb + j0 + 1) * 64 + ln] : z4;   // j0+1 <= 57 < 64
        wd[r] = rv ? xv4[(rb + j0 + 2) * 64 + ln] : z4;   // j0+2 <= 58 < 64
    }

    // ---- GEMM2: 8 px x 144 e; A from hs (row q8), B coalesced W2p ----
    f32x4 acc2[9];
    #pragma unroll
    for (int et = 0; et < 9; et++) {
        float bv = b2[et * 16 + r16];
        acc2[et] = (f32x4){bv, bv, bv, bv};
    }
    #pragma unroll
    for (int kk = 0; kk < 2; kk++) {
        int bcA = (kk * 64 + g * 16) ^ (q8 << 4);
        bf16x8 av = *(const bf16x8*)(arena + 4096 + q8 * 128 + bcA);
        #pragma unroll
        for (int et = 0; et < 9; et++) {
            bf16x8 bv = *(const bf16x8*)(w2p + (((kk * 9 + et) << 6) + ln) * 8);
            acc2[et] = __builtin_amdgcn_mfma_f32_16x16x32_bf16(av, bv, acc2[et], 0, 0, 0);
        }
    }

    // ---- ks: f32 transpose into wave arena (LDS only); acc2 dies here ----
    float* ksf = (float*)arena;                       // [8][148]
    #pragma unroll
    for (int et = 0; et < 9; et++) {
        #pragma unroll
        for (int r = 0; r < 4; r++) {
            int q = g * 4 + r;
            if (q < 8)
                ksf[q * 148 + et * 16 + r16] = acc2[et][r];
        }
    }

    // ---- involution: 4-column shift window, prefetch depth 2 ----
    const int s4 = (ln & 3) * 4;
    #pragma unroll
    for (int pp = 0; pp < 8; pp++) {
        const int j = j0 + pp;
        const float* kp = ksf + pp * 148 + s4;
        f32x4 o = {0.f, 0.f, 0.f, 0.f};
        #pragma unroll
        for (int r = 0; r < 3; r++) {
            o += (*(const f32x4*)(kp + (r * 3 + 0) * 16)) * wa[r];
            o += (*(const f32x4*)(kp + (r * 3 + 1) * 16)) * wb[r];
            o += (*(const f32x4*)(kp + (r * 3 + 2) * 16)) * wc[r];
        }
        __builtin_nontemporal_store(o, &((f32x4*)out)[(size_t)(pw + pp) * 64 + ln]);
        #pragma unroll
        for (int r = 0; r < 3; r++) { wa[r] = wb[r]; wb[r] = wc[r]; wc[r] = wd[r]; }
        if (pp < 6) {
            const int jn = j + 3;                      // consumed at pp+2
            const bool cv = jn < 64;
            #pragma unroll
            for (int r = 0; r < 3; r++) {
                int rw = i + r - 1;
                bool rv = (unsigned)rw < 64u;
                wd[r] = (rv && cv)
                    ? xv4[((size_t)(lb + r - 1) * 64 + jn) * 64 + ln] : z4;
            }
        }
    }

    // ---- coalesced ker epilogue: ksf -> contiguous NT stores (1152 f32) ----
    {
        float* kerW = ker + (size_t)pw * 144;   // wave's 1152 floats = 288 f32x4
        #pragma unroll
        for (int m = 0; m < 5; m++) {
            int fidx = m * 64 + ln;          // f32x4 index within wave region
            if (fidx < 288) {
                int rw   = fidx / 36;        // px row 0..7
                int col4 = fidx - rw * 36;   // f32x4 within row (144/4=36)
                f32x4 v = *(const f32x4*)(ksf + rw * 148 + col4 * 4);
                __builtin_nontemporal_store(v, (f32x4*)(kerW + fidx * 4));
            }
        }
    }
}

extern "C" void kernel_launch(void* const* d_in, const int* in_sizes, int n_in,
                              void* d_out, int out_size, void* d_ws, size_t ws_size,
                              hipStream_t stream) {
    const float* x     = (const float*)d_in[0];
    const float* W1    = (const float*)d_in[1];
    const float* b1    = (const float*)d_in[2];
    const float* gamma = (const float*)d_in[3];
    const float* beta  = (const float*)d_in[4];
    const float* mmean = (const float*)d_in[5];
    const float* mvar  = (const float*)d_in[6];
    const float* W2    = (const float*)d_in[7];
    const float* b2    = (const float*)d_in[8];

    float* out_main = (float*)d_out;                 // (B,H,W,C)   = 8388608 f32
    float* out_ker  = (float*)d_out + 8388608;       // (B,H,W,144) = 4718592 f32

    fold_kernel<<<64, 256, 0, stream>>>(W1, b1, gamma, beta, mmean, mvar, W2, d_ws);
    fused_kernel<<<NPIX / 32, 256, 0, stream>>>(x, d_ws, b2, out_ker, out_main);
}

// Round 18
// 26.934 us; speedup vs baseline: 1.2465x; 1.2465x over previous
//
#include <hip/hip_runtime.h>
#include <hip/hip_bf16.h>

typedef __attribute__((ext_vector_type(8))) short bf16x8;
typedef __attribute__((ext_vector_type(4))) float f32x4;

#define NPIX 32768

// ws byte layout (fragment-order packed weights):
//   [0, 32768)      W1p bf16: elem ((kk*4+dt)*64+ln)*8+cc  (kk<8, dt<4)
//   [32768, 51200)  W2p bf16: elem ((kk*9+et)*64+ln)*8+cc  (kk<2, et<9)
//   [51200, 51456)  b1f f32 [64]  (BN-folded bias)
// -> every MFMA B-fragment load is ONE coalesced 1KB wave access at a
//    wave-uniform base.

__device__ __forceinline__ ushort f2bf(float f) {
    __hip_bfloat16 h = __float2bfloat16(f);   // single v_cvt, RNE
    ushort u; __builtin_memcpy(&u, &h, 2);
    return u;
}

__global__ __launch_bounds__(256) void fold_kernel(
        const float* __restrict__ W1, const float* __restrict__ b1,
        const float* __restrict__ gamma, const float* __restrict__ beta,
        const float* __restrict__ mean, const float* __restrict__ var,
        const float* __restrict__ W2, void* __restrict__ ws) {
    ushort* w1p = (ushort*)ws;
    ushort* w2p = (ushort*)ws + 16384;
    float*  b1f = (float*)((char*)ws + 51200);
    int tid = blockIdx.x * 256 + threadIdx.x;
    if (tid < 16384) {
        int cc = tid & 7, ln = (tid >> 3) & 63, dt = (tid >> 9) & 3, kk = tid >> 11;
        int d = dt * 16 + (ln & 15);
        int c = kk * 32 + ((ln >> 4) & 3) * 8 + cc;
        float scale = gamma[d] * rsqrtf(var[d] + 1e-3f);
        w1p[tid] = f2bf(W1[c * 64 + d] * scale);
    }
    if (tid < 9216) {
        int cc = tid & 7, ln = (tid >> 3) & 63, rem = tid >> 9;  // rem<18
        int et = rem % 9, kk = rem / 9;
        int e = et * 16 + (ln & 15);
        int dcol = kk * 32 + ((ln >> 4) & 3) * 8 + cc;
        w2p[tid] = f2bf(W2[dcol * 144 + e]);
    }
    if (tid < 64) {
        float scale = gamma[tid] * rsqrtf(var[tid] + 1e-3f);
        b1f[tid] = (b1[tid] - mean[tid]) * scale + beta[tid];
    }
}

// R15 + W1p staged in BLOCK-SHARED LDS (one barrier at top).
// Rationale: W1p+W2p = 50KB > 32KB L1 -> 8 phase-skewed waves/CU thrash L1
// and every B-fragment load pays L2 latency in an in-order vmcnt chain.
// With W1p (32KB) in LDS, GEMM1 has ZERO vmem dependency (pure LDS+MFMA),
// and W2p (18KB) alone fits L1 -> L1-resident for GEMM2 across all waves.
// LDS: arenas 4 x 10240 @0 | W1s 32768 @40960  => 73728 B, 2 blocks/CU.
// Wave-private arenas (zero barriers after the top one):
//   phase A: xs bf16 [16 rows][512 B] @arena+0, swizzled   (x tile)
//   phase B: hs bf16 [16 rows][128 B] @arena+8192, swizzled (relu(h))
//   phase C: ks f32  [16 rows][148]   @arena+0 (aliases xs+hs -- safe:
//            written after all xs/hs LDS reads, per-wave in-order)
// Block = 1 image row (64 px), 4 waves, wave owns 16 px end-to-end.
// XCD k owns image k for halo L2 locality.
__global__ __launch_bounds__(256, 2) void fused_kernel(
        const float* __restrict__ x, const void* __restrict__ ws,
        const float* __restrict__ b2, float* __restrict__ ker,
        float* __restrict__ out) {
    __shared__ __align__(16) char smem[73728];
    const int t = threadIdx.x;
    const int wv = t >> 6, ln = t & 63;
    char* arena = smem + wv * 10240;
    char* w1s   = smem + 40960;                  // block-shared W1p copy
    const int bid = (int)blockIdx.x;
    const int lb = (bid & 7) * 64 + (bid >> 3);  // XCD k <- image k
    const int p0 = lb * 64;
    const ushort* w2p = (const ushort*)ws + 16384;
    const float*  b1f = (const float*)((const char*)ws + 51200);
    const int r16 = ln & 15, g = ln >> 4;

    // ---- stage W1p into block LDS (2048 x 16B chunks, 8 per thread) ----
    {
        const f32x4* wsrc = (const f32x4*)ws;
        f32x4* wdst = (f32x4*)w1s;
        #pragma unroll
        for (int m = 0; m < 8; m++)
            wdst[m * 256 + t] = wsrc[m * 256 + t];
    }

    // ---- stage wave's 16 x-rows: f32 -> bf16, XOR-swizzled, local rows ----
    {
        const float4* xg = (const float4*)(x + (size_t)(p0 + wv * 16) * 256);
        #pragma unroll
        for (int it = 0; it < 16; it++) {
            float4 v = xg[it * 64 + ln];
            ushort4 b4; b4.x = f2bf(v.x); b4.y = f2bf(v.y);
            b4.z = f2bf(v.z); b4.w = f2bf(v.w);
            int bcol = (ln * 8) ^ ((it & 7) << 4);
            *(ushort4*)(arena + it * 512 + bcol) = b4;
        }
    }
    __syncthreads();   // W1s visible to all waves (x staging is wave-private)

    // ---- GEMM1: 16 px x 64 d; A from arena xs, B from W1s (LDS) ----
    f32x4 acc[4];
    #pragma unroll
    for (int dt = 0; dt < 4; dt++) {
        float bv = b1f[dt * 16 + r16];
        acc[dt] = (f32x4){bv, bv, bv, bv};
    }
    #pragma unroll
    for (int kk = 0; kk < 8; kk++) {
        int bcA = (kk * 64 + g * 16) ^ ((r16 & 7) << 4);
        bf16x8 av = *(const bf16x8*)(arena + r16 * 512 + bcA);
        #pragma unroll
        for (int dt = 0; dt < 4; dt++) {
            bf16x8 bv = *(const bf16x8*)(w1s + (((kk * 4 + dt) << 6) + ln) * 16);
            acc[dt] = __builtin_amdgcn_mfma_f32_16x16x32_bf16(av, bv, acc[dt], 0, 0, 0);
        }
    }

    // relu -> bf16 -> hs (arena+8192, local rows 0..15, swizzled)
    #pragma unroll
    for (int dt = 0; dt < 4; dt++) {
        #pragma unroll
        for (int r = 0; r < 4; r++) {
            int q = g * 4 + r;                        // local px (C/D row)
            int bcol = ((dt * 16 + r16) * 2) ^ ((q & 7) << 4);
            *(ushort*)(arena + 8192 + q * 128 + bcol) = f2bf(fmaxf(acc[dt][r], 0.f));
        }
    }

    // ---- invol window preload: latency hides under GEMM2 ----
    const int i  = lb & 63;
    const f32x4* xv4 = (const f32x4*)x;
    const int j0 = wv * 16;
    const f32x4 z4 = {0.f, 0.f, 0.f, 0.f};
    f32x4 wa[3], wb[3], wc[3], wd[3];   // cols j-1, j, j+1, j+2
    #pragma unroll
    for (int r = 0; r < 3; r++) {
        int row = i + r - 1;
        bool rv = (unsigned)row < 64u;
        const size_t rb = (size_t)(lb + r - 1) * 64;
        wa[r] = (rv && j0 > 0) ? xv4[(rb + (j0 - 1)) * 64 + ln] : z4;
        wb[r] = rv ? xv4[(rb + j0) * 64 + ln] : z4;
        wc[r] = rv ? xv4[(rb + j0 + 1) * 64 + ln] : z4;   // j0+1 <= 49 < 64
        wd[r] = rv ? xv4[(rb + j0 + 2) * 64 + ln] : z4;   // j0+2 <= 50 < 64
    }

    // ---- GEMM2: 16 px x 144 e; A from hs, B from W2p (L1-resident 18KB) ----
    f32x4 acc2[9];
    #pragma unroll
    for (int et = 0; et < 9; et++) {
        float bv = b2[et * 16 + r16];
        acc2[et] = (f32x4){bv, bv, bv, bv};
    }
    #pragma unroll
    for (int kk = 0; kk < 2; kk++) {
        int bcA = (kk * 64 + g * 16) ^ ((r16 & 7) << 4);
        bf16x8 av = *(const bf16x8*)(arena + 8192 + r16 * 128 + bcA);
        #pragma unroll
        for (int et = 0; et < 9; et++) {
            bf16x8 bv = *(const bf16x8*)(w2p + (((kk * 9 + et) << 6) + ln) * 8);
            acc2[et] = __builtin_amdgcn_mfma_f32_16x16x32_bf16(av, bv, acc2[et], 0, 0, 0);
        }
    }

    // ---- ks: f32 transpose into wave arena (LDS only); acc2 dies here ----
    float* ksf = (float*)arena;                       // [16][148]
    #pragma unroll
    for (int et = 0; et < 9; et++) {
        #pragma unroll
        for (int r = 0; r < 4; r++) {
            int q = g * 4 + r;
            ksf[q * 148 + et * 16 + r16] = acc2[et][r];
        }
    }

    // ---- involution: 4-column shift window, prefetch depth 2 ----
    const int s4 = (ln & 3) * 4;
    #pragma unroll 4
    for (int pp = 0; pp < 16; pp++) {
        const int j = j0 + pp;
        const float* kp = ksf + pp * 148 + s4;
        f32x4 o = {0.f, 0.f, 0.f, 0.f};
        #pragma unroll
        for (int r = 0; r < 3; r++) {
            o += (*(const f32x4*)(kp + (r * 3 + 0) * 16)) * wa[r];
            o += (*(const f32x4*)(kp + (r * 3 + 1) * 16)) * wb[r];
            o += (*(const f32x4*)(kp + (r * 3 + 2) * 16)) * wc[r];
        }
        __builtin_nontemporal_store(o, &((f32x4*)out)[(size_t)(p0 + j) * 64 + ln]);
        #pragma unroll
        for (int r = 0; r < 3; r++) { wa[r] = wb[r]; wb[r] = wc[r]; wc[r] = wd[r]; }
        if (pp < 14) {
            const int jn = j + 3;                      // consumed at pp+2
            const bool cv = jn < 64;
            #pragma unroll
            for (int r = 0; r < 3; r++) {
                int row = i + r - 1;
                bool rv = (unsigned)row < 64u;
                wd[r] = (rv && cv)
                    ? xv4[((size_t)(lb + r - 1) * 64 + jn) * 64 + ln] : z4;
            }
        }
    }

    // ---- coalesced ker epilogue: ksf -> 9 x 1KB contiguous NT stores ----
    {
        float* kerW = ker + (size_t)(p0 + wv * 16) * 144;   // wave's 2304 floats
        #pragma unroll
        for (int m = 0; m < 9; m++) {
            int fidx = m * 64 + ln;          // f32x4 index within wave region
            int row  = fidx / 36;            // px row 0..15
            int col4 = fidx - row * 36;      // f32x4 within row (144/4=36)
            f32x4 v = *(const f32x4*)(ksf + row * 148 + col4 * 4);
            __builtin_nontemporal_store(v, (f32x4*)(kerW + fidx * 4));
        }
    }
}

extern "C" void kernel_launch(void* const* d_in, const int* in_sizes, int n_in,
                              void* d_out, int out_size, void* d_ws, size_t ws_size,
                              hipStream_t stream) {
    const float* x     = (const float*)d_in[0];
    const float* W1    = (const float*)d_in[1];
    const float* b1    = (const float*)d_in[2];
    const float* gamma = (const float*)d_in[3];
    const float* beta  = (const float*)d_in[4];
    const float* mmean = (const float*)d_in[5];
    const float* mvar  = (const float*)d_in[6];
    const float* W2    = (const float*)d_in[7];
    const float* b2    = (const float*)d_in[8];

    float* out_main = (float*)d_out;                 // (B,H,W,C)   = 8388608 f32
    float* out_ker  = (float*)d_out + 8388608;       // (B,H,W,144) = 4718592 f32

    fold_kernel<<<64, 256, 0, stream>>>(W1, b1, gamma, beta, mmean, mvar, W2, d_ws);
    fused_kernel<<<NPIX / 64, 256, 0, stream>>>(x, d_ws, b2, out_ker, out_main);
}

// Round 19
// 26.374 us; speedup vs baseline: 1.2730x; 1.0212x over previous
//
#include <hip/hip_runtime.h>
#include <hip/hip_bf16.h>

typedef __attribute__((ext_vector_type(8))) short bf16x8;
typedef __attribute__((ext_vector_type(4))) float f32x4;

#define NPIX 32768

// ws byte layout (fragment-order packed weights):
//   [0, 32768)      W1p bf16: elem ((kk*4+dt)*64+ln)*8+cc  (kk<8, dt<4)
//   [32768, 51200)  W2p bf16: elem ((kk*9+et)*64+ln)*8+cc  (kk<2, et<9)
//   [51200, 51456)  b1f f32 [64]  (BN-folded bias)

__device__ __forceinline__ ushort f2bf(float f) {
    __hip_bfloat16 h = __float2bfloat16(f);   // single v_cvt, RNE
    ushort u; __builtin_memcpy(&u, &h, 2);
    return u;
}

__global__ __launch_bounds__(256) void fold_kernel(
        const float* __restrict__ W1, const float* __restrict__ b1,
        const float* __restrict__ gamma, const float* __restrict__ beta,
        const float* __restrict__ mean, const float* __restrict__ var,
        const float* __restrict__ W2, void* __restrict__ ws) {
    ushort* w1p = (ushort*)ws;
    ushort* w2p = (ushort*)ws + 16384;
    float*  b1f = (float*)((char*)ws + 51200);
    int tid = blockIdx.x * 256 + threadIdx.x;
    if (tid < 16384) {
        int cc = tid & 7, ln = (tid >> 3) & 63, dt = (tid >> 9) & 3, kk = tid >> 11;
        int d = dt * 16 + (ln & 15);
        int c = kk * 32 + ((ln >> 4) & 3) * 8 + cc;
        float scale = gamma[d] * rsqrtf(var[d] + 1e-3f);
        w1p[tid] = f2bf(W1[c * 64 + d] * scale);
    }
    if (tid < 9216) {
        int cc = tid & 7, ln = (tid >> 3) & 63, rem = tid >> 9;  // rem<18
        int et = rem % 9, kk = rem / 9;
        int e = et * 16 + (ln & 15);
        int dcol = kk * 32 + ((ln >> 4) & 3) * 8 + cc;
        w2p[tid] = f2bf(W2[dcol * 144 + e]);
    }
    if (tid < 64) {
        float scale = gamma[tid] * rsqrtf(var[tid] + 1e-3f);
        b1f[tid] = (b1[tid] - mean[tid]) * scale + beta[tid];
    }
}

// R18 + 2-ROW BLOCK: 128 px, 512 threads (8 waves); wave = (row-half,
// col-quarter), still 16 px/wave end-to-end. Gains vs R18:
//  - W1s staged once per 128 px (256 blocks instead of 512): half the
//    L2->LDS weight traffic and half the staging barrier drains;
//  - invol halo: 2-row block reads 4 x-rows instead of 2x3 -> -33% tap
//    traffic through L1/L2.
// LDS: 8 arenas x 10240 @0 | W1s 32768 @81920 => 114688 B, 1 block/CU
// (8 waves/CU -- same wave concurrency as R18's 2x4).
// Wave-private arenas (one barrier after W1s+x staging, zero after):
//   phase A: xs bf16 [16 rows][512 B] @arena+0, swizzled   (x tile)
//   phase B: hs bf16 [16 rows][128 B] @arena+8192, swizzled (relu(h))
//   phase C: ks f32  [16 rows][148]   @arena+0 (aliases xs+hs -- safe:
//            written after all xs/hs LDS reads, per-wave in-order)
// XCD k owns image k for halo L2 locality. GEMM2 B from W2p global
// (18KB, L1-resident alone).
__global__ __launch_bounds__(512, 2) void fused_kernel(
        const float* __restrict__ x, const void* __restrict__ ws,
        const float* __restrict__ b2, float* __restrict__ ker,
        float* __restrict__ out) {
    __shared__ __align__(16) char smem[114688];
    const int t = threadIdx.x;
    const int wv = t >> 6, ln = t & 63;
    char* arena = smem + wv * 10240;
    char* w1s   = smem + 81920;                  // block-shared W1p copy
    const int bid = (int)blockIdx.x;
    const int img = bid & 7;                     // XCD k <- image k
    const int rp  = bid >> 3;                    // row pair 0..31
    const int i   = rp * 2 + (wv >> 2);          // image row of this wave
    const int lb  = img * 64 + i;                // b*64 + i
    const int j0  = (wv & 3) * 16;               // wave's first column
    const int pw  = lb * 64 + j0;                // wave's first pixel
    const ushort* w2p = (const ushort*)ws + 16384;
    const float*  b1f = (const float*)((const char*)ws + 51200);
    const int r16 = ln & 15, g = ln >> 4;

    // ---- stage W1p into block LDS (2048 x 16B chunks, 4 per thread) ----
    {
        const f32x4* wsrc = (const f32x4*)ws;
        f32x4* wdst = (f32x4*)w1s;
        #pragma unroll
        for (int m = 0; m < 4; m++)
            wdst[m * 512 + t] = wsrc[m * 512 + t];
    }

    // ---- stage wave's 16 x-rows: f32 -> bf16, XOR-swizzled, local rows ----
    {
        const float4* xg = (const float4*)(x + (size_t)pw * 256);
        #pragma unroll
        for (int it = 0; it < 16; it++) {
            float4 v = xg[it * 64 + ln];
            ushort4 b4; b4.x = f2bf(v.x); b4.y = f2bf(v.y);
            b4.z = f2bf(v.z); b4.w = f2bf(v.w);
            int bcol = (ln * 8) ^ ((it & 7) << 4);
            *(ushort4*)(arena + it * 512 + bcol) = b4;
        }
    }
    __syncthreads();   // W1s visible to all waves (x staging is wave-private)

    // ---- GEMM1: 16 px x 64 d; A from arena xs, B from W1s (LDS) ----
    f32x4 acc[4];
    #pragma unroll
    for (int dt = 0; dt < 4; dt++) {
        float bv = b1f[dt * 16 + r16];
        acc[dt] = (f32x4){bv, bv, bv, bv};
    }
    #pragma unroll
    for (int kk = 0; kk < 8; kk++) {
        int bcA = (kk * 64 + g * 16) ^ ((r16 & 7) << 4);
        bf16x8 av = *(const bf16x8*)(arena + r16 * 512 + bcA);
        #pragma unroll
        for (int dt = 0; dt < 4; dt++) {
            bf16x8 bv = *(const bf16x8*)(w1s + (((kk * 4 + dt) << 6) + ln) * 16);
            acc[dt] = __builtin_amdgcn_mfma_f32_16x16x32_bf16(av, bv, acc[dt], 0, 0, 0);
        }
    }

    // relu -> bf16 -> hs (arena+8192, local rows 0..15, swizzled)
    #pragma unroll
    for (int dt = 0; dt < 4; dt++) {
        #pragma unroll
        for (int r = 0; r < 4; r++) {
            int q = g * 4 + r;                        // local px (C/D row)
            int bcol = ((dt * 16 + r16) * 2) ^ ((q & 7) << 4);
            *(ushort*)(arena + 8192 + q * 128 + bcol) = f2bf(fmaxf(acc[dt][r], 0.f));
        }
    }

    // ---- invol window preload: latency hides under GEMM2 ----
    const f32x4* xv4 = (const f32x4*)x;
    const f32x4 z4 = {0.f, 0.f, 0.f, 0.f};
    f32x4 wa[3], wb[3], wc[3], wd[3];   // cols j-1, j, j+1, j+2
    #pragma unroll
    for (int r = 0; r < 3; r++) {
        int row = i + r - 1;
        bool rv = (unsigned)row < 64u;
        const size_t rb = (size_t)(lb + r - 1) * 64;
        wa[r] = (rv && j0 > 0) ? xv4[(rb + (j0 - 1)) * 64 + ln] : z4;
        wb[r] = rv ? xv4[(rb + j0) * 64 + ln] : z4;
        wc[r] = rv ? xv4[(rb + j0 + 1) * 64 + ln] : z4;   // j0+1 <= 49 < 64
        wd[r] = rv ? xv4[(rb + j0 + 2) * 64 + ln] : z4;   // j0+2 <= 50 < 64
    }

    // ---- GEMM2: 16 px x 144 e; A from hs, B from W2p (L1-resident 18KB) ----
    f32x4 acc2[9];
    #pragma unroll
    for (int et = 0; et < 9; et++) {
        float bv = b2[et * 16 + r16];
        acc2[et] = (f32x4){bv, bv, bv, bv};
    }
    #pragma unroll
    for (int kk = 0; kk < 2; kk++) {
        int bcA = (kk * 64 + g * 16) ^ ((r16 & 7) << 4);
        bf16x8 av = *(const bf16x8*)(arena + 8192 + r16 * 128 + bcA);
        #pragma unroll
        for (int et = 0; et < 9; et++) {
            bf16x8 bv = *(const bf16x8*)(w2p + (((kk * 9 + et) << 6) + ln) * 8);
            acc2[et] = __builtin_amdgcn_mfma_f32_16x16x32_bf16(av, bv, acc2[et], 0, 0, 0);
        }
    }

    // ---- ks: f32 transpose into wave arena (LDS only); acc2 dies here ----
    float* ksf = (float*)arena;                       // [16][148]
    #pragma unroll
    for (int et = 0; et < 9; et++) {
        #pragma unroll
        for (int r = 0; r < 4; r++) {
            int q = g * 4 + r;
            ksf[q * 148 + et * 16 + r16] = acc2[et][r];
        }
    }

    // ---- involution: 4-column shift window, prefetch depth 2 ----
    const int s4 = (ln & 3) * 4;
    #pragma unroll 4
    for (int pp = 0; pp < 16; pp++) {
        const int j = j0 + pp;
        const float* kp = ksf + pp * 148 + s4;
        f32x4 o = {0.f, 0.f, 0.f, 0.f};
        #pragma unroll
        for (int r = 0; r < 3; r++) {
            o += (*(const f32x4*)(kp + (r * 3 + 0) * 16)) * wa[r];
            o += (*(const f32x4*)(kp + (r * 3 + 1) * 16)) * wb[r];
            o += (*(const f32x4*)(kp + (r * 3 + 2) * 16)) * wc[r];
        }
        __builtin_nontemporal_store(o, &((f32x4*)out)[(size_t)(lb * 64 + j) * 64 + ln]);
        #pragma unroll
        for (int r = 0; r < 3; r++) { wa[r] = wb[r]; wb[r] = wc[r]; wc[r] = wd[r]; }
        if (pp < 14) {
            const int jn = j + 3;                      // consumed at pp+2
            const bool cv = jn < 64;
            #pragma unroll
            for (int r = 0; r < 3; r++) {
                int row = i + r - 1;
                bool rv = (unsigned)row < 64u;
                wd[r] = (rv && cv)
                    ? xv4[((size_t)(lb + r - 1) * 64 + jn) * 64 + ln] : z4;
            }
        }
    }

    // ---- coalesced ker epilogue: ksf -> 9 x 1KB contiguous NT stores ----
    {
        float* kerW = ker + (size_t)pw * 144;   // wave's 2304 floats
        #pragma unroll
        for (int m = 0; m < 9; m++) {
            int fidx = m * 64 + ln;          // f32x4 index within wave region
            int row  = fidx / 36;            // px row 0..15
            int col4 = fidx - row * 36;      // f32x4 within row (144/4=36)
            f32x4 v = *(const f32x4*)(ksf + row * 148 + col4 * 4);
            __builtin_nontemporal_store(v, (f32x4*)(kerW + fidx * 4));
        }
    }
}

extern "C" void kernel_launch(void* const* d_in, const int* in_sizes, int n_in,
                              void* d_out, int out_size, void* d_ws, size_t ws_size,
                              hipStream_t stream) {
    const float* x     = (const float*)d_in[0];
    const float* W1    = (const float*)d_in[1];
    const float* b1    = (const float*)d_in[2];
    const float* gamma = (const float*)d_in[3];
    const float* beta  = (const float*)d_in[4];
    const float* mmean = (const float*)d_in[5];
    const float* mvar  = (const float*)d_in[6];
    const float* W2    = (const float*)d_in[7];
    const float* b2    = (const float*)d_in[8];

    float* out_main = (float*)d_out;                 // (B,H,W,C)   = 8388608 f32
    float* out_ker  = (float*)d_out + 8388608;       // (B,H,W,144) = 4718592 f32

    fold_kernel<<<64, 256, 0, stream>>>(W1, b1, gamma, beta, mmean, mvar, W2, d_ws);
    fused_kernel<<<NPIX / 128, 512, 0, stream>>>(x, d_ws, b2, out_ker, out_main);
}

// Round 20
// 25.599 us; speedup vs baseline: 1.3116x; 1.0303x over previous
//
#include <hip/hip_runtime.h>
#include <hip/hip_bf16.h>

typedef __attribute__((ext_vector_type(8))) short bf16x8;
typedef __attribute__((ext_vector_type(4))) float f32x4;

#define NPIX 32768

// ws byte layout (fragment-order packed weights):
//   [0, 32768)      W1p bf16: elem ((kk*4+dt)*64+ln)*8+cc  (kk<8, dt<4)
//   [32768, 51200)  W2p bf16: elem ((kk*9+et)*64+ln)*8+cc  (kk<2, et<9)
//   [51200, 51456)  b1f f32 [64]  (BN-folded bias)

__device__ __forceinline__ ushort f2bf(float f) {
    __hip_bfloat16 h = __float2bfloat16(f);   // single v_cvt, RNE
    ushort u; __builtin_memcpy(&u, &h, 2);
    return u;
}

__global__ __launch_bounds__(256) void fold_kernel(
        const float* __restrict__ W1, const float* __restrict__ b1,
        const float* __restrict__ gamma, const float* __restrict__ beta,
        const float* __restrict__ mean, const float* __restrict__ var,
        const float* __restrict__ W2, void* __restrict__ ws) {
    ushort* w1p = (ushort*)ws;
    ushort* w2p = (ushort*)ws + 16384;
    float*  b1f = (float*)((char*)ws + 51200);
    int tid = blockIdx.x * 256 + threadIdx.x;
    if (tid < 16384) {
        int cc = tid & 7, ln = (tid >> 3) & 63, dt = (tid >> 9) & 3, kk = tid >> 11;
        int d = dt * 16 + (ln & 15);
        int c = kk * 32 + ((ln >> 4) & 3) * 8 + cc;
        float scale = gamma[d] * rsqrtf(var[d] + 1e-3f);
        w1p[tid] = f2bf(W1[c * 64 + d] * scale);
    }
    if (tid < 9216) {
        int cc = tid & 7, ln = (tid >> 3) & 63, rem = tid >> 9;  // rem<18
        int et = rem % 9, kk = rem / 9;
        int e = et * 16 + (ln & 15);
        int dcol = kk * 32 + ((ln >> 4) & 3) * 8 + cc;
        w2p[tid] = f2bf(W2[dcol * 144 + e]);
    }
    if (tid < 64) {
        float scale = gamma[tid] * rsqrtf(var[tid] + 1e-3f);
        b1f[tid] = (b1[tid] - mean[tid]) * scale + beta[tid];
    }
}

// R19 + W2p ALSO staged in block LDS: GEMM2, like GEMM1, now has zero vmem
// dependency (L1 is thrashed by x streaming, so W2p global loads were L2-
// latency chains despite "fits L1" -- same mechanism R18 fixed for W1).
// Block = 2 image rows, 128 px, 512 threads (8 waves); wave = (row-half,
// col-quarter), 16 px end-to-end.
// LDS: 8 arenas x 10240 @0 | W1s 32768 @81920 | W2s 18432 @114688
//   => 133120 B, 1 block/CU (8 waves/CU).
// Wave-private arenas (one barrier after weight+x staging, zero after):
//   phase A: xs bf16 [16 rows][512 B] @arena+0, swizzled   (x tile)
//   phase B: hs bf16 [16 rows][128 B] @arena+8192, swizzled (relu(h))
//   phase C: ks f32  [16 rows][148]   @arena+0 (aliases xs+hs -- safe:
//            written after all xs/hs LDS reads, per-wave in-order)
// XCD k owns image k for halo L2 locality.
__global__ __launch_bounds__(512, 1) void fused_kernel(
        const float* __restrict__ x, const void* __restrict__ ws,
        const float* __restrict__ b2, float* __restrict__ ker,
        float* __restrict__ out) {
    __shared__ __align__(16) char smem[133120];
    const int t = threadIdx.x;
    const int wv = t >> 6, ln = t & 63;
    char* arena = smem + wv * 10240;
    char* w1s   = smem + 81920;                  // block-shared W1p copy
    char* w2s   = smem + 114688;                 // block-shared W2p copy
    const int bid = (int)blockIdx.x;
    const int img = bid & 7;                     // XCD k <- image k
    const int rp  = bid >> 3;                    // row pair 0..31
    const int i   = rp * 2 + (wv >> 2);          // image row of this wave
    const int lb  = img * 64 + i;                // b*64 + i
    const int j0  = (wv & 3) * 16;               // wave's first column
    const int pw  = lb * 64 + j0;                // wave's first pixel
    const float*  b1f = (const float*)((const char*)ws + 51200);
    const int r16 = ln & 15, g = ln >> 4;

    // ---- stage W1p + W2p into block LDS (coalesced 16B chunks) ----
    {
        const f32x4* wsrc = (const f32x4*)ws;
        f32x4* wdst1 = (f32x4*)w1s;
        #pragma unroll
        for (int m = 0; m < 4; m++)
            wdst1[m * 512 + t] = wsrc[m * 512 + t];    // 2048 chunks
        f32x4* wdst2 = (f32x4*)w2s;
        #pragma unroll
        for (int m = 0; m < 3; m++) {
            int idx = m * 512 + t;
            if (idx < 1152)
                wdst2[idx] = wsrc[2048 + idx];         // 1152 chunks
        }
    }

    // ---- stage wave's 16 x-rows: f32 -> bf16, XOR-swizzled, local rows ----
    {
        const float4* xg = (const float4*)(x + (size_t)pw * 256);
        #pragma unroll
        for (int it = 0; it < 16; it++) {
            float4 v = xg[it * 64 + ln];
            ushort4 b4; b4.x = f2bf(v.x); b4.y = f2bf(v.y);
            b4.z = f2bf(v.z); b4.w = f2bf(v.w);
            int bcol = (ln * 8) ^ ((it & 7) << 4);
            *(ushort4*)(arena + it * 512 + bcol) = b4;
        }
    }
    __syncthreads();   // W1s/W2s visible to all waves (x staging wave-private)

    // ---- GEMM1: 16 px x 64 d; A from arena xs, B from W1s (LDS) ----
    f32x4 acc[4];
    #pragma unroll
    for (int dt = 0; dt < 4; dt++) {
        float bv = b1f[dt * 16 + r16];
        acc[dt] = (f32x4){bv, bv, bv, bv};
    }
    #pragma unroll
    for (int kk = 0; kk < 8; kk++) {
        int bcA = (kk * 64 + g * 16) ^ ((r16 & 7) << 4);
        bf16x8 av = *(const bf16x8*)(arena + r16 * 512 + bcA);
        #pragma unroll
        for (int dt = 0; dt < 4; dt++) {
            bf16x8 bv = *(const bf16x8*)(w1s + (((kk * 4 + dt) << 6) + ln) * 16);
            acc[dt] = __builtin_amdgcn_mfma_f32_16x16x32_bf16(av, bv, acc[dt], 0, 0, 0);
        }
    }

    // relu -> bf16 -> hs (arena+8192, local rows 0..15, swizzled)
    #pragma unroll
    for (int dt = 0; dt < 4; dt++) {
        #pragma unroll
        for (int r = 0; r < 4; r++) {
            int q = g * 4 + r;                        // local px (C/D row)
            int bcol = ((dt * 16 + r16) * 2) ^ ((q & 7) << 4);
            *(ushort*)(arena + 8192 + q * 128 + bcol) = f2bf(fmaxf(acc[dt][r], 0.f));
        }
    }

    // ---- invol window preload: latency hides under GEMM2 ----
    const f32x4* xv4 = (const f32x4*)x;
    const f32x4 z4 = {0.f, 0.f, 0.f, 0.f};
    f32x4 wa[3], wb[3], wc[3], wd[3];   // cols j-1, j, j+1, j+2
    #pragma unroll
    for (int r = 0; r < 3; r++) {
        int row = i + r - 1;
        bool rv = (unsigned)row < 64u;
        const size_t rb = (size_t)(lb + r - 1) * 64;
        wa[r] = (rv && j0 > 0) ? xv4[(rb + (j0 - 1)) * 64 + ln] : z4;
        wb[r] = rv ? xv4[(rb + j0) * 64 + ln] : z4;
        wc[r] = rv ? xv4[(rb + j0 + 1) * 64 + ln] : z4;   // j0+1 <= 49 < 64
        wd[r] = rv ? xv4[(rb + j0 + 2) * 64 + ln] : z4;   // j0+2 <= 50 < 64
    }

    // ---- GEMM2: 16 px x 144 e; A from hs, B from W2s (LDS) ----
    f32x4 acc2[9];
    #pragma unroll
    for (int et = 0; et < 9; et++) {
        float bv = b2[et * 16 + r16];
        acc2[et] = (f32x4){bv, bv, bv, bv};
    }
    #pragma unroll
    for (int kk = 0; kk < 2; kk++) {
        int bcA = (kk * 64 + g * 16) ^ ((r16 & 7) << 4);
        bf16x8 av = *(const bf16x8*)(arena + 8192 + r16 * 128 + bcA);
        #pragma unroll
        for (int et = 0; et < 9; et++) {
            bf16x8 bv = *(const bf16x8*)(w2s + (((kk * 9 + et) << 6) + ln) * 16);
            acc2[et] = __builtin_amdgcn_mfma_f32_16x16x32_bf16(av, bv, acc2[et], 0, 0, 0);
        }
    }

    // ---- ks: f32 transpose into wave arena (LDS only); acc2 dies here ----
    float* ksf = (float*)arena;                       // [16][148]
    #pragma unroll
    for (int et = 0; et < 9; et++) {
        #pragma unroll
        for (int r = 0; r < 4; r++) {
            int q = g * 4 + r;
            ksf[q * 148 + et * 16 + r16] = acc2[et][r];
        }
    }

    // ---- involution: 4-column shift window, prefetch depth 2 ----
    const int s4 = (ln & 3) * 4;
    #pragma unroll 4
    for (int pp = 0; pp < 16; pp++) {
        const int j = j0 + pp;
        const float* kp = ksf + pp * 148 + s4;
        f32x4 o = {0.f, 0.f, 0.f, 0.f};
        #pragma unroll
        for (int r = 0; r < 3; r++) {
            o += (*(const f32x4*)(kp + (r * 3 + 0) * 16)) * wa[r];
            o += (*(const f32x4*)(kp + (r * 3 + 1) * 16)) * wb[r];
            o += (*(const f32x4*)(kp + (r * 3 + 2) * 16)) * wc[r];
        }
        __builtin_nontemporal_store(o, &((f32x4*)out)[(size_t)(lb * 64 + j) * 64 + ln]);
        #pragma unroll
        for (int r = 0; r < 3; r++) { wa[r] = wb[r]; wb[r] = wc[r]; wc[r] = wd[r]; }
        if (pp < 14) {
            const int jn = j + 3;                      // consumed at pp+2
            const bool cv = jn < 64;
            #pragma unroll
            for (int r = 0; r < 3; r++) {
                int row = i + r - 1;
                bool rv = (unsigned)row < 64u;
                wd[r] = (rv && cv)
                    ? xv4[((size_t)(lb + r - 1) * 64 + jn) * 64 + ln] : z4;
            }
        }
    }

    // ---- coalesced ker epilogue: ksf -> 9 x 1KB contiguous NT stores ----
    {
        float* kerW = ker + (size_t)pw * 144;   // wave's 2304 floats
        #pragma unroll
        for (int m = 0; m < 9; m++) {
            int fidx = m * 64 + ln;          // f32x4 index within wave region
            int row  = fidx / 36;            // px row 0..15
            int col4 = fidx - row * 36;      // f32x4 within row (144/4=36)
            f32x4 v = *(const f32x4*)(ksf + row * 148 + col4 * 4);
            __builtin_nontemporal_store(v, (f32x4*)(kerW + fidx * 4));
        }
    }
}

extern "C" void kernel_launch(void* const* d_in, const int* in_sizes, int n_in,
                              void* d_out, int out_size, void* d_ws, size_t ws_size,
                              hipStream_t stream) {
    const float* x     = (const float*)d_in[0];
    const float* W1    = (const float*)d_in[1];
    const float* b1    = (const float*)d_in[2];
    const float* gamma = (const float*)d_in[3];
    const float* beta  = (const float*)d_in[4];
    const float* mmean = (const float*)d_in[5];
    const float* mvar  = (const float*)d_in[6];
    const float* W2    = (const float*)d_in[7];
    const float* b2    = (const float*)d_in[8];

    float* out_main = (float*)d_out;                 // (B,H,W,C)   = 8388608 f32
    float* out_ker  = (float*)d_out + 8388608;       // (B,H,W,144) = 4718592 f32

    fold_kernel<<<64, 256, 0, stream>>>(W1, b1, gamma, beta, mmean, mvar, W2, d_ws);
    fused_kernel<<<NPIX / 128, 512, 0, stream>>>(x, d_ws, b2, out_ker, out_main);
}

// Round 21
// 21.181 us; speedup vs baseline: 1.5851x; 1.2086x over previous
//
#include <hip/hip_runtime.h>
#include <hip/hip_bf16.h>

typedef __attribute__((ext_vector_type(8))) short bf16x8;
typedef __attribute__((ext_vector_type(4))) float f32x4;

#define NPIX 32768

__device__ __forceinline__ ushort f2bf(float f) {
    __hip_bfloat16 h = __float2bfloat16(f);   // single v_cvt, RNE
    ushort u; __builtin_memcpy(&u, &h, 2);
    return u;
}

// Single fused kernel (fold merged in): each block repacks W1/W2 directly
// from global into its own LDS copies (fragment order, BN-folded) -- the
// ~50 scattered 4B loads/thread hit the L2/L3-resident 100KB weight arrays
// and hide under the HBM-bound x staging. Removes the fold kernel, its
// launch gap, and the ws round-trip (~3 us of serialized time).
// Fragment-packed layout (same as before):
//   w1s chunk idx = ((kk*4+dt)*64+ln), 16B: W1[c*64+d]*scale, d=dt*16+(ln&15),
//       c=kk*32+(ln>>4)*8+cc, cc=0..7
//   w2s chunk idx = ((kk*9+et)*64+ln): W2[dcol*144+e], e=et*16+(ln&15),
//       dcol=kk*32+(ln>>4)*8+cc
// Block = 2 image rows, 128 px, 512 threads (8 waves); wave = (row-half,
// col-quarter), 16 px end-to-end.
// LDS: 8 arenas x 10240 @0 | W1s 32768 @81920 | W2s 18432 @114688
//   => 133120 B, 1 block/CU (8 waves/CU).
// Wave-private arenas (one barrier after weight+x staging, zero after):
//   phase A: xs bf16 [16 rows][512 B] @arena+0, swizzled   (x tile)
//   phase B: hs bf16 [16 rows][128 B] @arena+8192, swizzled (relu(h))
//   phase C: ks f32  [16 rows][148]   @arena+0 (aliases xs+hs -- safe:
//            written after all xs/hs LDS reads, per-wave in-order)
// XCD k owns image k for halo L2 locality.
__global__ __launch_bounds__(512, 1) void fused_kernel(
        const float* __restrict__ x,
        const float* __restrict__ W1, const float* __restrict__ b1,
        const float* __restrict__ gamma, const float* __restrict__ beta,
        const float* __restrict__ mean, const float* __restrict__ var,
        const float* __restrict__ W2, const float* __restrict__ b2,
        float* __restrict__ ker, float* __restrict__ out) {
    __shared__ __align__(16) char smem[133120];
    const int t = threadIdx.x;
    const int wv = t >> 6, ln = t & 63;
    char* arena = smem + wv * 10240;
    char* w1s   = smem + 81920;                  // block-shared packed W1
    char* w2s   = smem + 114688;                 // block-shared packed W2
    const int bid = (int)blockIdx.x;
    const int img = bid & 7;                     // XCD k <- image k
    const int rp  = bid >> 3;                    // row pair 0..31
    const int i   = rp * 2 + (wv >> 2);          // image row of this wave
    const int lb  = img * 64 + i;                // b*64 + i
    const int j0  = (wv & 3) * 16;               // wave's first column
    const int pw  = lb * 64 + j0;                // wave's first pixel
    const int r16 = ln & 15, g = ln >> 4;

    // ---- repack W1 -> w1s (2048 x 16B chunks, 4 per thread) ----
    #pragma unroll
    for (int m = 0; m < 4; m++) {
        int idx = m * 512 + t;
        int ln2 = idx & 63, dt = (idx >> 6) & 3, kk = idx >> 8;
        int d = dt * 16 + (ln2 & 15);
        float sc = gamma[d] * rsqrtf(var[d] + 1e-3f);
        int cbase = kk * 32 + (ln2 >> 4) * 8;
        ushort tmp[8];
        #pragma unroll
        for (int cc = 0; cc < 8; cc++)
            tmp[cc] = f2bf(W1[(cbase + cc) * 64 + d] * sc);
        __builtin_memcpy(w1s + idx * 16, tmp, 16);
    }
    // ---- repack W2 -> w2s (1152 x 16B chunks) ----
    #pragma unroll
    for (int m = 0; m < 3; m++) {
        int idx = m * 512 + t;
        if (idx < 1152) {
            int ln2 = idx & 63, rem = idx >> 6;   // rem < 18
            int et = rem % 9, kk = rem / 9;
            int e = et * 16 + (ln2 & 15);
            int dbase = kk * 32 + (ln2 >> 4) * 8;
            ushort tmp[8];
            #pragma unroll
            for (int cc = 0; cc < 8; cc++)
                tmp[cc] = f2bf(W2[(dbase + cc) * 144 + e]);
            __builtin_memcpy(w2s + idx * 16, tmp, 16);
        }
    }
    // ---- per-thread BN-folded bias (L1-hot 256B arrays) ----
    float b1fv[4];
    #pragma unroll
    for (int dt = 0; dt < 4; dt++) {
        int d = dt * 16 + r16;
        float sc = gamma[d] * rsqrtf(var[d] + 1e-3f);
        b1fv[dt] = (b1[d] - mean[d]) * sc + beta[d];
    }

    // ---- stage wave's 16 x-rows: f32 -> bf16, XOR-swizzled, local rows ----
    {
        const float4* xg = (const float4*)(x + (size_t)pw * 256);
        #pragma unroll
        for (int it = 0; it < 16; it++) {
            float4 v = xg[it * 64 + ln];
            ushort4 b4; b4.x = f2bf(v.x); b4.y = f2bf(v.y);
            b4.z = f2bf(v.z); b4.w = f2bf(v.w);
            int bcol = (ln * 8) ^ ((it & 7) << 4);
            *(ushort4*)(arena + it * 512 + bcol) = b4;
        }
    }
    __syncthreads();   // w1s/w2s visible to all waves (x staging wave-private)

    // ---- GEMM1: 16 px x 64 d; A from arena xs, B from w1s (LDS) ----
    f32x4 acc[4];
    #pragma unroll
    for (int dt = 0; dt < 4; dt++) {
        float bv = b1fv[dt];
        acc[dt] = (f32x4){bv, bv, bv, bv};
    }
    #pragma unroll
    for (int kk = 0; kk < 8; kk++) {
        int bcA = (kk * 64 + g * 16) ^ ((r16 & 7) << 4);
        bf16x8 av = *(const bf16x8*)(arena + r16 * 512 + bcA);
        #pragma unroll
        for (int dt = 0; dt < 4; dt++) {
            bf16x8 bv = *(const bf16x8*)(w1s + (((kk * 4 + dt) << 6) + ln) * 16);
            acc[dt] = __builtin_amdgcn_mfma_f32_16x16x32_bf16(av, bv, acc[dt], 0, 0, 0);
        }
    }

    // relu -> bf16 -> hs (arena+8192, local rows 0..15, swizzled)
    #pragma unroll
    for (int dt = 0; dt < 4; dt++) {
        #pragma unroll
        for (int r = 0; r < 4; r++) {
            int q = g * 4 + r;                        // local px (C/D row)
            int bcol = ((dt * 16 + r16) * 2) ^ ((q & 7) << 4);
            *(ushort*)(arena + 8192 + q * 128 + bcol) = f2bf(fmaxf(acc[dt][r], 0.f));
        }
    }

    // ---- invol window preload: latency hides under GEMM2 ----
    const f32x4* xv4 = (const f32x4*)x;
    const f32x4 z4 = {0.f, 0.f, 0.f, 0.f};
    f32x4 wa[3], wb[3], wc[3], wd[3];   // cols j-1, j, j+1, j+2
    #pragma unroll
    for (int r = 0; r < 3; r++) {
        int row = i + r - 1;
        bool rv = (unsigned)row < 64u;
        const size_t rb = (size_t)(lb + r - 1) * 64;
        wa[r] = (rv && j0 > 0) ? xv4[(rb + (j0 - 1)) * 64 + ln] : z4;
        wb[r] = rv ? xv4[(rb + j0) * 64 + ln] : z4;
        wc[r] = rv ? xv4[(rb + j0 + 1) * 64 + ln] : z4;   // j0+1 <= 49 < 64
        wd[r] = rv ? xv4[(rb + j0 + 2) * 64 + ln] : z4;   // j0+2 <= 50 < 64
    }

    // ---- GEMM2: 16 px x 144 e; A from hs, B from w2s (LDS) ----
    f32x4 acc2[9];
    #pragma unroll
    for (int et = 0; et < 9; et++) {
        float bv = b2[et * 16 + r16];
        acc2[et] = (f32x4){bv, bv, bv, bv};
    }
    #pragma unroll
    for (int kk = 0; kk < 2; kk++) {
        int bcA = (kk * 64 + g * 16) ^ ((r16 & 7) << 4);
        bf16x8 av = *(const bf16x8*)(arena + 8192 + r16 * 128 + bcA);
        #pragma unroll
        for (int et = 0; et < 9; et++) {
            bf16x8 bv = *(const bf16x8*)(w2s + (((kk * 9 + et) << 6) + ln) * 16);
            acc2[et] = __builtin_amdgcn_mfma_f32_16x16x32_bf16(av, bv, acc2[et], 0, 0, 0);
        }
    }

    // ---- ks: f32 transpose into wave arena (LDS only); acc2 dies here ----
    float* ksf = (float*)arena;                       // [16][148]
    #pragma unroll
    for (int et = 0; et < 9; et++) {
        #pragma unroll
        for (int r = 0; r < 4; r++) {
            int q = g * 4 + r;
            ksf[q * 148 + et * 16 + r16] = acc2[et][r];
        }
    }

    // ---- involution: 4-column shift window, prefetch depth 2 ----
    const int s4 = (ln & 3) * 4;
    #pragma unroll 4
    for (int pp = 0; pp < 16; pp++) {
        const int j = j0 + pp;
        const float* kp = ksf + pp * 148 + s4;
        f32x4 o = {0.f, 0.f, 0.f, 0.f};
        #pragma unroll
        for (int r = 0; r < 3; r++) {
            o += (*(const f32x4*)(kp + (r * 3 + 0) * 16)) * wa[r];
            o += (*(const f32x4*)(kp + (r * 3 + 1) * 16)) * wb[r];
            o += (*(const f32x4*)(kp + (r * 3 + 2) * 16)) * wc[r];
        }
        __builtin_nontemporal_store(o, &((f32x4*)out)[(size_t)(lb * 64 + j) * 64 + ln]);
        #pragma unroll
        for (int r = 0; r < 3; r++) { wa[r] = wb[r]; wb[r] = wc[r]; wc[r] = wd[r]; }
        if (pp < 14) {
            const int jn = j + 3;                      // consumed at pp+2
            const bool cv = jn < 64;
            #pragma unroll
            for (int r = 0; r < 3; r++) {
                int row = i + r - 1;
                bool rv = (unsigned)row < 64u;
                wd[r] = (rv && cv)
                    ? xv4[((size_t)(lb + r - 1) * 64 + jn) * 64 + ln] : z4;
            }
        }
    }

    // ---- coalesced ker epilogue: ksf -> 9 x 1KB contiguous NT stores ----
    {
        float* kerW = ker + (size_t)pw * 144;   // wave's 2304 floats
        #pragma unroll
        for (int m = 0; m < 9; m++) {
            int fidx = m * 64 + ln;          // f32x4 index within wave region
            int row  = fidx / 36;            // px row 0..15
            int col4 = fidx - row * 36;      // f32x4 within row (144/4=36)
            f32x4 v = *(const f32x4*)(ksf + row * 148 + col4 * 4);
            __builtin_nontemporal_store(v, (f32x4*)(kerW + fidx * 4));
        }
    }
}

extern "C" void kernel_launch(void* const* d_in, const int* in_sizes, int n_in,
                              void* d_out, int out_size, void* d_ws, size_t ws_size,
                              hipStream_t stream) {
    const float* x     = (const float*)d_in[0];
    const float* W1    = (const float*)d_in[1];
    const float* b1    = (const float*)d_in[2];
    const float* gamma = (const float*)d_in[3];
    const float* beta  = (const float*)d_in[4];
    const float* mmean = (const float*)d_in[5];
    const float* mvar  = (const float*)d_in[6];
    const float* W2    = (const float*)d_in[7];
    const float* b2    = (const float*)d_in[8];

    float* out_main = (float*)d_out;                 // (B,H,W,C)   = 8388608 f32
    float* out_ker  = (float*)d_out + 8388608;       // (B,H,W,144) = 4718592 f32

    fused_kernel<<<NPIX / 128, 512, 0, stream>>>(
        x, W1, b1, gamma, beta, mmean, mvar, W2, b2, out_ker, out_main);
}